// Round 3
// baseline (323.320 us; speedup 1.0000x reference)
//
#include <hip/hip_runtime.h>

#define TWO_PI 6.283185307179586f

typedef _Float16 half8 __attribute__((ext_vector_type(8)));
typedef _Float16 half4 __attribute__((ext_vector_type(4)));
typedef float floatx4 __attribute__((ext_vector_type(4)));

// async global->LDS, 16B per lane. LDS dest = wave-uniform base + lane*16.
__device__ __forceinline__ void async16(const _Float16* g, _Float16* l) {
    __builtin_amdgcn_global_load_lds(
        (const __attribute__((address_space(1))) void*)g,
        (__attribute__((address_space(3))) void*)l, 16, 0, 0);
}

// ------------------------------------------------------------------
// Transpose+convert core: src fp32 [K][N] -> dst f16 [N][K], 64x64 tile
// ------------------------------------------------------------------
__device__ __forceinline__ void transpose_core(
    const float* __restrict__ src, _Float16* __restrict__ dst,
    int K, int N, _Float16* t, int bx, int by)
{
    int n0 = bx * 64, k0 = by * 64;
    int tid = threadIdx.x;          // 256
    int r = tid >> 4;               // 0..15
    int c4 = (tid & 15) * 4;
#pragma unroll
    for (int p = 0; p < 4; p++) {
        int k = r + p*16;
        float4 v = *(const float4*)(src + (size_t)(k0+k)*N + n0 + c4);
        t[(c4+0)*68 + k] = (_Float16)v.x;
        t[(c4+1)*68 + k] = (_Float16)v.y;
        t[(c4+2)*68 + k] = (_Float16)v.z;
        t[(c4+3)*68 + k] = (_Float16)v.w;
    }
    __syncthreads();
    int ck = (tid & 15) * 4;
#pragma unroll
    for (int p = 0; p < 4; p++) {
        int n = r + p*16;
        half4 v = *(const half4*)(t + n*68 + ck);
        *(half4*)(dst + (size_t)(n0+n)*K + k0 + ck) = v;
    }
}

// ------------------------------------------------------------------
// Mega prep kernel (single launch, no inter-block deps):
//   [0,192)     transpose_w1 (box K=256 / click K=512)
//   [192,2240)  per-row blocks (2048): box IoU-argmax match (1 proposal
//               per thread, block argmax reduce, first-max tiebreak) +
//               click NN argmin (16 pts/thread, first-min tiebreak) +
//               feature gathers + fourier pos embed + prompt mask.
// (w2 transposes moved into the gemm_l1 launch -- only gemm_l2 needs them)
// ------------------------------------------------------------------
__global__ void mega_prep(
    const float* __restrict__ logits, const float* __restrict__ corners,
    const float* __restrict__ box_query,
    const float* __restrict__ bw1, const float* __restrict__ cw1,
    _Float16* __restrict__ w1t_box, _Float16* __restrict__ w1t_clk,
    const float* __restrict__ prop_features,
    const float* __restrict__ enc_features,
    const float* __restrict__ enc_xyz,
    const float* __restrict__ cq,
    const float* __restrict__ pc_min,
    const float* __restrict__ pc_max,
    const float* __restrict__ gB,
    const float* __restrict__ box_qmask,
    const float* __restrict__ click_qmask,
    _Float16* __restrict__ box_in,
    _Float16* __restrict__ click_in,
    float* __restrict__ out)
{
    __shared__ float smem[2176];            // 8704 B transpose tile
    __shared__ float nnd[4]; __shared__ int nni[4];
    __shared__ float bxd[4]; __shared__ int bxi[4];
    __shared__ int s_nn, s_match;
    int bid = blockIdx.x;
    if (bid < 192) {
        // transpose_w1: grid (12,8,2); box branch only y<4 (K=256)
        _Float16* tb = (_Float16*)smem;
        int x = bid % 12, y = (bid / 12) % 8, z = bid / 96;
        if (z == 0) {
            if (y < 4) transpose_core(bw1, w1t_box, 256, 768, tb, x, y);
        } else {
            transpose_core(cw1, w1t_clk, 512, 768, tb, x, y);
        }
        return;
    }

    // ---------------- per-row block ----------------
    int row = bid - 192;      // 0..2047  (== b*64 + q)
    int t = threadIdx.x;      // 256
    int b = row >> 6;
    int lane = t & 63, wave = t >> 6;

    // ---- click NN over 4096 points, 16 pts/thread ----
    float cx = cq[row*3+0];
    float cy = cq[row*3+1];
    float cz = cq[row*3+2];
    const float* ex = enc_xyz + (size_t)b * 4096 * 3;
    float nbest = 3.4e38f; int nbidx = 0;
#pragma unroll
    for (int i = 0; i < 16; i++) {
        int p = t + i*256;
        float dx = cx - ex[p*3+0];
        float dy = cy - ex[p*3+1];
        float dz = cz - ex[p*3+2];
        float d = dx*dx + dy*dy;
        d = d + dz*dz;
        if (d < nbest) { nbest = d; nbidx = p; }   // strict <, p ascending -> first min
    }
#pragma unroll
    for (int off = 32; off; off >>= 1) {
        float ov = __shfl_down(nbest, off);
        int   oi = __shfl_down(nbidx, off);
        if (ov < nbest || (ov == nbest && oi < nbidx)) { nbest = ov; nbidx = oi; }
    }
    if (lane == 0) { nnd[wave] = nbest; nni[wave] = nbidx; }

    // ---- box match: this thread owns proposal p = t ----
    float iou; int pidx = t;
    {
        const float* c = corners + ((size_t)b*256 + t) * 24;
        float mn0 = c[0], mn1 = c[1], mn2 = c[2];
        float mx0 = mn0, mx1 = mn1, mx2 = mn2;
#pragma unroll
        for (int k = 1; k < 8; k++) {
            float v0 = c[k*3+0], v1 = c[k*3+1], v2 = c[k*3+2];
            mn0 = fminf(mn0, v0); mx0 = fmaxf(mx0, v0);
            mn1 = fminf(mn1, v1); mx1 = fmaxf(mx1, v1);
            mn2 = fminf(mn2, v2); mx2 = fmaxf(mx2, v2);
        }
        float pvol = (mx0-mn0)*(mx1-mn1)*(mx2-mn2);
        const float* lg = logits + ((size_t)b*256 + t) * 19;
        float bv = lg[0]; int bi = 0;
#pragma unroll
        for (int k = 1; k < 19; k++) { float v = lg[k]; if (v > bv) { bv = v; bi = k; } }
        float pmsk = (bi != 18) ? 1.0f : 0.0f;

        // query AABB (same for all threads in block)
        const float* qc = box_query + (size_t)row * 24;
        float qn0 = qc[0], qn1 = qc[1], qn2 = qc[2];
        float qx0 = qn0, qx1 = qn1, qx2 = qn2;
#pragma unroll
        for (int k = 1; k < 8; k++) {
            float v0 = qc[k*3+0], v1 = qc[k*3+1], v2 = qc[k*3+2];
            qn0 = fminf(qn0, v0); qx0 = fmaxf(qx0, v0);
            qn1 = fminf(qn1, v1); qx1 = fmaxf(qx1, v1);
            qn2 = fminf(qn2, v2); qx2 = fmaxf(qx2, v2);
        }
        float qvol = (qx0-qn0)*(qx1-qn1)*(qx2-qn2);
        float e0 = fminf(qx0, mx0) - fmaxf(qn0, mn0); e0 = fmaxf(e0, 0.0f);
        float e1 = fminf(qx1, mx1) - fmaxf(qn1, mn1); e1 = fmaxf(e1, 0.0f);
        float e2 = fminf(qx2, mx2) - fmaxf(qn2, mn2); e2 = fmaxf(e2, 0.0f);
        float inter = (e0*e1)*e2;
        iou = inter / (qvol + pvol - inter + 1e-8f) * pmsk;
    }
#pragma unroll
    for (int off = 32; off; off >>= 1) {
        float ov = __shfl_down(iou, off);
        int   oi = __shfl_down(pidx, off);
        if (ov > iou || (ov == iou && oi < pidx)) { iou = ov; pidx = oi; }
    }
    if (lane == 0) { bxd[wave] = iou; bxi[wave] = pidx; }
    __syncthreads();
    if (t == 0) {
        float nv = nnd[0]; int ni = nni[0];
        float bv = bxd[0]; int bi = bxi[0];
#pragma unroll
        for (int w = 1; w < 4; w++) {
            if (nnd[w] < nv || (nnd[w] == nv && nni[w] < ni)) { nv = nnd[w]; ni = nni[w]; }
            if (bxd[w] > bv || (bxd[w] == bv && bxi[w] < bi)) { bv = bxd[w]; bi = bxi[w]; }
        }
        s_nn = ni; s_match = bi;
    }
    __syncthreads();
    int nnid = s_nn, match = s_match;

    // ---- gathers + fourier pos embed ----
    box_in[(size_t)row*256 + t] =
        (_Float16)prop_features[((size_t)b*256 + match)*256 + t];
    click_in[(size_t)row*512 + t] =
        (_Float16)enc_features[((size_t)b*4096 + nnid)*256 + t];
    int j = t & 127;
    float m0 = pc_min[b*3+0], m1 = pc_min[b*3+1], m2 = pc_min[b*3+2];
    float tx = (cx - m0) / (pc_max[b*3+0] - m0) * TWO_PI;
    float ty = (cy - m1) / (pc_max[b*3+1] - m1) * TWO_PI;
    float tz = (cz - m2) / (pc_max[b*3+2] - m2) * TWO_PI;
    float p = tx * gB[j] + ty * gB[128+j] + tz * gB[256+j];
    float v = (t < 128) ? sinf(p) : cosf(p);
    click_in[(size_t)row*512 + 256 + t] = (_Float16)v;
    // prompt mask: 16 elements per row-block
    if (t < 16) {
        int idx = row*16 + t;            // 0..32767
        int mb = idx >> 10, i = idx & 1023;
        float mv = (i < 512) ? box_qmask[mb*64 + (i >> 3)]
                             : click_qmask[mb*64 + ((i - 512) >> 3)];
        out[25165824 + idx] = mv;
    }
}

// ------------------------------------------------------------------
// f16 MFMA GEMM core (128x128 tile, verified): used by layer-1.
// C[M,N] = A[M,K] @ Bt[N,K]^T + bias, relu -> f16 Hout (row-major).
// ------------------------------------------------------------------
template<int MODE>
__device__ __forceinline__ void gemm_core(
    const _Float16* __restrict__ A, const _Float16* __restrict__ Bt,
    const float* __restrict__ bias, int N, int K,
    _Float16* __restrict__ Hout, float* __restrict__ Fout, long brOff,
    int bm, int bn, _Float16* As, _Float16* Bs)
{
    const int tid = threadIdx.x;
    const int wave = tid >> 6, lane = tid & 63;
    const int waveM = (wave & 1) * 64, waveN = (wave >> 1) * 64;
    const int nrow = lane & 15;         // fragment row within 16
    const int kq   = lane >> 4;         // fragment k quarter (0..3)

    const int srow = tid >> 3;                                  // 0..31
    const int jdat = ((tid & 7) ^ (srow & 7)) * 8;              // half offset

    floatx4 acc[4][4];
#pragma unroll
    for (int i = 0; i < 4; i++)
#pragma unroll
        for (int j = 0; j < 4; j++) { floatx4 z = {0.f,0.f,0.f,0.f}; acc[i][j] = z; }

    const _Float16* Ab[4]; const _Float16* Bb[4];
    _Float16 *lA[4], *lB[4];
#pragma unroll
    for (int q = 0; q < 4; q++) {
        Ab[q] = A  + (size_t)(bm*128 + q*32 + srow) * K + jdat;
        Bb[q] = Bt + (size_t)(bn*128 + q*32 + srow) * K + jdat;
        lA[q] = As + q*2048 + wave*512;
        lB[q] = Bs + q*2048 + wave*512;
    }

    for (int kk = 0; kk < K; kk += 64) {
        __syncthreads();                 // prior-tile LDS reads done
#pragma unroll
        for (int q = 0; q < 4; q++) async16(Ab[q] + kk, lA[q]);
#pragma unroll
        for (int q = 0; q < 4; q++) async16(Bb[q] + kk, lB[q]);
        __syncthreads();                 // staging complete
#pragma unroll
        for (int h = 0; h < 2; h++) {
            const int sw = (((kq + h*4) ^ (nrow & 7)) * 8);
            half8 af[4], bf[4];
#pragma unroll
            for (int i = 0; i < 4; i++)
                af[i] = *(const half8*)(As + (waveM + i*16 + nrow)*64 + sw);
#pragma unroll
            for (int j = 0; j < 4; j++)
                bf[j] = *(const half8*)(Bs + (waveN + j*16 + nrow)*64 + sw);
#pragma unroll
            for (int i = 0; i < 4; i++)
#pragma unroll
                for (int j = 0; j < 4; j++)
                    acc[i][j] = __builtin_amdgcn_mfma_f32_16x16x32_f16(af[i], bf[j], acc[i][j], 0, 0, 0);
        }
    }

#pragma unroll
    for (int i = 0; i < 4; i++) {
#pragma unroll
        for (int j = 0; j < 4; j++) {
            int col = bn*128 + waveN + j*16 + nrow;
            float bv = bias[col];
#pragma unroll
            for (int r = 0; r < 4; r++) {
                int row = bm*128 + waveM + i*16 + kq*4 + r;
                float v = acc[i][j][r] + bv;
                if (MODE == 0) {
                    v = v > 0.f ? v : 0.f;
                    Hout[(size_t)row * N + col] = (_Float16)v;
                } else {
                    size_t off = (size_t)(row >> 6) * 786432 + (size_t)brOff
                               + (size_t)(row & 63) * 6144 + col;
                    Fout[off] = v;
                }
            }
        }
    }
}

// ------------------------------------------------------------------
// Launch 2: layer-1 GEMM blocks [0,192) + w2 transposes [192,2496).
// No dependency between the two halves; the 2304 transpose blocks
// fill the machine while the 192 GEMM blocks run.
// ------------------------------------------------------------------
__global__ __launch_bounds__(256) void gemm_l1_t2(
    const _Float16* __restrict__ A0, const _Float16* __restrict__ A1,
    const _Float16* __restrict__ B0, const _Float16* __restrict__ B1,
    const float* __restrict__ b0, const float* __restrict__ b1,
    _Float16* __restrict__ H0, _Float16* __restrict__ H1,
    const float* __restrict__ bw2, const float* __restrict__ cw2,
    _Float16* __restrict__ w2t_box, _Float16* __restrict__ w2t_clk)
{
    __shared__ _Float16 As[8192];
    __shared__ _Float16 Bs[8192];
    int bid = blockIdx.x;
    if (bid < 192) {
        int z = bid / 96, r = bid % 96;
        int bm = r % 16, bn = r / 16;     // (16,6)
        if (z == 0)
            gemm_core<0>(A0, B0, b0, 768, 256, H0, nullptr, 0, bm, bn, As, Bs);
        else
            gemm_core<0>(A1, B1, b1, 768, 512, H1, nullptr, 0, bm, bn, As, Bs);
    } else {
        int r = bid - 192;                // 0..2303 = (96,12,2)
        int x = r % 96, y = (r / 96) % 12, z = r / 1152;
        if (z == 0) transpose_core(bw2, w2t_box, 768, 6144, As, x, y);
        else        transpose_core(cw2, w2t_clk, 768, 6144, As, x, y);
    }
}

// ------------------------------------------------------------------
// Layer-2 GEMM: 256x256 tile, BK=64, counted-vmcnt double-buffer
// pipeline (T3/T4/T5). 512 thr = 8 waves (2M x 4N), per-wave 128x64.
// LDS 128 KiB (2 buf x (A 32K + B 32K)), XOR-swizzled (same scheme as
// the verified 128^2 core: slot jslot holds data k-block jslot^(row&7)).
//
// Pipeline protocol (per wave; K=768 -> NT=12 tiles):
//   prologue: STAGE(t0->buf0) STAGE(t1->buf1); vmcnt(8); barrier
//   iter t:   read B frags + A frags (4 chunks x 16 MFMA, setprio-wrapped);
//             before last chunk: lgkmcnt(0); barrier;   <- all waves done
//             if t<NT-2: STAGE(t+2 -> buf[t&1])          reading buf[t&1]
//             last MFMA chunk (overlaps load issue);
//             vmcnt(8) [t<NT-2] else vmcnt(0); barrier  <- buf[t^1] landed
// vmcnt never drains to 0 in steady state; raw s_barrier avoids the
// __syncthreads full vmcnt(0) drain. Numerics identical to 128^2 core
// (same fragment K-order).
// ------------------------------------------------------------------
__global__ __launch_bounds__(512, 2) void gemm_l2_8p(
    const _Float16* __restrict__ A0, const _Float16* __restrict__ A1,
    const _Float16* __restrict__ B0, const _Float16* __restrict__ B1,
    const float* __restrict__ b0, const float* __restrict__ b1,
    float* __restrict__ out)
{
    __shared__ _Float16 As[2][16384];   // [buf][256 rows x 64 halves]
    __shared__ _Float16 Bs[2][16384];

    // XCD-contiguous bijective remap (384 % 8 == 0): each XCD gets
    // 48 consecutive wgs = 6 bn-cols x 8 bm -> A panel (3MB) L2-resident.
    int lin = blockIdx.x;                     // 0..383
    int wg  = (lin & 7) * 48 + (lin >> 3);
    int br  = wg / 192;
    int r   = wg % 192;
    int bn  = r >> 3;                         // 0..23
    int bm  = r & 7;                          // 0..7
    const _Float16* A  = br ? A1 : A0;
    const _Float16* Bt = br ? B1 : B0;
    const float* bias  = br ? b1 : b0;
    long brOff = br ? 393216 : 0;

    const int tid  = threadIdx.x;
    const int wave = tid >> 6, lane = tid & 63;
    const int waveM = (wave & 1) * 128;       // 2 M-halves
    const int waveN = (wave >> 1) * 64;       // 4 N-quarters
    const int nrow = lane & 15;
    const int kq   = lane >> 4;

    // staging map: thread -> (row = q*64 + srow, slot = tid&7),
    // global k-block jdat = (slot ^ (srow&7)); LDS dest linear per wave.
    const int srow = tid >> 3;                // 0..63
    const int jdat = ((tid & 7) ^ (srow & 7)) * 8;
    const int ldst = wave * 512;              // halves

    const _Float16* Ag[4]; const _Float16* Bg[4];
#pragma unroll
    for (int q = 0; q < 4; q++) {
        Ag[q] = A  + (size_t)(bm*256 + q*64 + srow) * 768 + jdat;
        Bg[q] = Bt + (size_t)(bn*256 + q*64 + srow) * 768 + jdat;
    }

    floatx4 acc[8][4];
#pragma unroll
    for (int i = 0; i < 8; i++)
#pragma unroll
        for (int j = 0; j < 4; j++) { floatx4 z = {0.f,0.f,0.f,0.f}; acc[i][j] = z; }

    const int sw0 = ((kq    ) ^ (nrow & 7)) * 8;
    const int sw1 = ((kq + 4) ^ (nrow & 7)) * 8;
    int aoff[8], boff[4];
#pragma unroll
    for (int i = 0; i < 8; i++) aoff[i] = (waveM + i*16 + nrow) * 64;
#pragma unroll
    for (int j = 0; j < 4; j++) boff[j] = (waveN + j*16 + nrow) * 64;

#define STAGE_TILE(kk, c) do {                                        \
    _Float16* asd = &As[c][0]; _Float16* bsd = &Bs[c][0];             \
    _Pragma("unroll")                                                 \
    for (int q = 0; q < 4; q++) async16(Ag[q] + (kk), asd + q*4096 + ldst); \
    _Pragma("unroll")                                                 \
    for (int q = 0; q < 4; q++) async16(Bg[q] + (kk), bsd + q*4096 + ldst); \
} while (0)

    // prologue: tiles 0,1 in flight; wait tile0 (8 newest outstanding)
    STAGE_TILE(0, 0);
    STAGE_TILE(64, 1);
    asm volatile("s_waitcnt vmcnt(8)" ::: "memory");
    __builtin_amdgcn_s_barrier();

    for (int t = 0; t < 12; ++t) {
        const int cur = t & 1;
        const _Float16* as = &As[cur][0];
        const _Float16* bs = &Bs[cur][0];
        half8 bf[4][2];
#pragma unroll
        for (int j = 0; j < 4; j++) {
            bf[j][0] = *(const half8*)(bs + boff[j] + sw0);
            bf[j][1] = *(const half8*)(bs + boff[j] + sw1);
        }
#pragma unroll
        for (int c = 0; c < 4; c++) {
            half8 af[2][2];
#pragma unroll
            for (int m = 0; m < 2; m++) {
                af[m][0] = *(const half8*)(as + aoff[2*c+m] + sw0);
                af[m][1] = *(const half8*)(as + aoff[2*c+m] + sw1);
            }
            if (c == 3) {
                // all of buf[cur] consumed by this wave -> drain, sync,
                // then overwrite buf[cur] with tile t+2.
                asm volatile("s_waitcnt lgkmcnt(0)" ::: "memory");
                __builtin_amdgcn_s_barrier();
                if (t < 10) STAGE_TILE((t + 2) * 64, cur);
            }
            __builtin_amdgcn_s_setprio(1);
#pragma unroll
            for (int m = 0; m < 2; m++)
#pragma unroll
                for (int j = 0; j < 4; j++) {
                    acc[2*c+m][j] = __builtin_amdgcn_mfma_f32_16x16x32_f16(
                        af[m][0], bf[j][0], acc[2*c+m][j], 0, 0, 0);
                    acc[2*c+m][j] = __builtin_amdgcn_mfma_f32_16x16x32_f16(
                        af[m][1], bf[j][1], acc[2*c+m][j], 0, 0, 0);
                }
            __builtin_amdgcn_s_setprio(0);
        }
        // ensure tile t+1 (buf[cur^1]) landed; keep t+2's 8 loads in flight
        if (t < 10) { asm volatile("s_waitcnt vmcnt(8)" ::: "memory"); }
        else        { asm volatile("s_waitcnt vmcnt(0)" ::: "memory"); }
        __builtin_amdgcn_s_barrier();
    }
#undef STAGE_TILE

    // epilogue: C/D layout col = lane&15, row = (lane>>4)*4 + reg
#pragma unroll
    for (int i = 0; i < 8; i++) {
#pragma unroll
        for (int j = 0; j < 4; j++) {
            int col = bn*256 + waveN + j*16 + nrow;
            float bv = bias[col];
#pragma unroll
            for (int rr = 0; rr < 4; rr++) {
                int row = bm*256 + waveM + i*16 + kq*4 + rr;
                size_t off = (size_t)(row >> 6) * 786432 + (size_t)brOff
                           + (size_t)(row & 63) * 6144 + col;
                out[off] = acc[i][j][rr] + bv;
            }
        }
    }
}

// ------------------------------------------------------------------
extern "C" void kernel_launch(void* const* d_in, const int* in_sizes, int n_in,
                              void* d_out, int out_size, void* d_ws, size_t ws_size,
                              hipStream_t stream)
{
    const float* sem   = (const float*)d_in[0];
    const float* propf = (const float*)d_in[1];
    const float* boxc  = (const float*)d_in[2];
    const float* encx  = (const float*)d_in[3];
    const float* encf  = (const float*)d_in[4];
    const float* pcmin = (const float*)d_in[5];
    const float* pcmax = (const float*)d_in[6];
    const float* boxq  = (const float*)d_in[7];
    const float* boxm  = (const float*)d_in[8];
    const float* clkq  = (const float*)d_in[9];
    const float* clkm  = (const float*)d_in[10];
    const float* gB    = (const float*)d_in[11];
    const float* bw1   = (const float*)d_in[12];
    const float* bb1   = (const float*)d_in[13];
    const float* bw2   = (const float*)d_in[14];
    const float* bb2   = (const float*)d_in[15];
    const float* cw1   = (const float*)d_in[16];
    const float* cb1   = (const float*)d_in[17];
    const float* cw2   = (const float*)d_in[18];
    const float* cb2   = (const float*)d_in[19];
    float* out = (float*)d_out;
    char* ws = (char*)d_ws;

    _Float16* box_in   = (_Float16*)(ws + 278528);    // 2048x256
    _Float16* click_in = (_Float16*)(ws + 1327104);   // 2048x512
    _Float16* h_box    = (_Float16*)(ws + 3424256);   // 2048x768
    _Float16* h_click  = (_Float16*)(ws + 6569984);   // 2048x768
    _Float16* w1t_box  = (_Float16*)(ws + 9715712);   // 768x256
    _Float16* w2t_box  = (_Float16*)(ws + 10108928);  // 6144x768
    _Float16* w1t_clk  = (_Float16*)(ws + 19546112);  // 768x512
    _Float16* w2t_clk  = (_Float16*)(ws + 20332544);  // 6144x768

    // K1: w1 transposes + per-row front-end
    mega_prep<<<2240, 256, 0, stream>>>(sem, boxc, boxq,
                                        bw1, cw1, w1t_box, w1t_clk,
                                        propf, encf, encx, clkq,
                                        pcmin, pcmax, gB, boxm, clkm,
                                        box_in, click_in, out);
    // K2: layer-1 GEMM + w2 transposes (independent, one launch)
    gemm_l1_t2<<<2496, 256, 0, stream>>>(box_in, click_in, w1t_box, w1t_clk,
                                         bb1, cb1, h_box, h_click,
                                         bw2, cw2, w2t_box, w2t_clk);
    // K3: layer-2 GEMM, 256^2 counted-vmcnt pipeline
    gemm_l2_8p<<<384, 512, 0, stream>>>(h_box, h_click, w2t_box, w2t_clk,
                                        bb2, cb2, out);
}

// Round 6
// 316.818 us; speedup vs baseline: 1.0205x; 1.0205x over previous
//
#include <hip/hip_runtime.h>

#define TWO_PI 6.283185307179586f

typedef _Float16 half8 __attribute__((ext_vector_type(8)));
typedef _Float16 half4 __attribute__((ext_vector_type(4)));
typedef float floatx4 __attribute__((ext_vector_type(4)));

// async global->LDS, 16B per lane. LDS dest = wave-uniform base + lane*16.
__device__ __forceinline__ void async16(const _Float16* g, _Float16* l) {
    __builtin_amdgcn_global_load_lds(
        (const __attribute__((address_space(1))) void*)g,
        (__attribute__((address_space(3))) void*)l, 16, 0, 0);
}

// ------------------------------------------------------------------
// Transpose+convert core: src fp32 [K][N] -> dst f16 [N][K], 64x64 tile
// ------------------------------------------------------------------
__device__ __forceinline__ void transpose_core(
    const float* __restrict__ src, _Float16* __restrict__ dst,
    int K, int N, _Float16* t, int bx, int by)
{
    int n0 = bx * 64, k0 = by * 64;
    int tid = threadIdx.x;          // 256
    int r = tid >> 4;               // 0..15
    int c4 = (tid & 15) * 4;
#pragma unroll
    for (int p = 0; p < 4; p++) {
        int k = r + p*16;
        float4 v = *(const float4*)(src + (size_t)(k0+k)*N + n0 + c4);
        t[(c4+0)*68 + k] = (_Float16)v.x;
        t[(c4+1)*68 + k] = (_Float16)v.y;
        t[(c4+2)*68 + k] = (_Float16)v.z;
        t[(c4+3)*68 + k] = (_Float16)v.w;
    }
    __syncthreads();
    int ck = (tid & 15) * 4;
#pragma unroll
    for (int p = 0; p < 4; p++) {
        int n = r + p*16;
        half4 v = *(const half4*)(t + n*68 + ck);
        *(half4*)(dst + (size_t)(n0+n)*K + k0 + ck) = v;
    }
}

// ------------------------------------------------------------------
// Mega prep kernel (single launch, no inter-block deps):
//   [0,192)     transpose_w1 (box K=256 / click K=512)
//   [192,2240)  per-row blocks (2048): box IoU-argmax match (1 proposal
//               per thread, block argmax reduce, first-max tiebreak) +
//               click NN argmin (16 pts/thread, first-min tiebreak) +
//               feature gathers + fourier pos embed + prompt mask.
// ------------------------------------------------------------------
__global__ void mega_prep(
    const float* __restrict__ logits, const float* __restrict__ corners,
    const float* __restrict__ box_query,
    const float* __restrict__ bw1, const float* __restrict__ cw1,
    _Float16* __restrict__ w1t_box, _Float16* __restrict__ w1t_clk,
    const float* __restrict__ prop_features,
    const float* __restrict__ enc_features,
    const float* __restrict__ enc_xyz,
    const float* __restrict__ cq,
    const float* __restrict__ pc_min,
    const float* __restrict__ pc_max,
    const float* __restrict__ gB,
    const float* __restrict__ box_qmask,
    const float* __restrict__ click_qmask,
    _Float16* __restrict__ box_in,
    _Float16* __restrict__ click_in,
    float* __restrict__ out)
{
    __shared__ float smem[2176];            // 8704 B transpose tile
    __shared__ float nnd[4]; __shared__ int nni[4];
    __shared__ float bxd[4]; __shared__ int bxi[4];
    __shared__ int s_nn, s_match;
    int bid = blockIdx.x;
    if (bid < 192) {
        // transpose_w1: grid (12,8,2); box branch only y<4 (K=256)
        _Float16* tb = (_Float16*)smem;
        int x = bid % 12, y = (bid / 12) % 8, z = bid / 96;
        if (z == 0) {
            if (y < 4) transpose_core(bw1, w1t_box, 256, 768, tb, x, y);
        } else {
            transpose_core(cw1, w1t_clk, 512, 768, tb, x, y);
        }
        return;
    }

    // ---------------- per-row block ----------------
    int row = bid - 192;      // 0..2047  (== b*64 + q)
    int t = threadIdx.x;      // 256
    int b = row >> 6;
    int lane = t & 63, wave = t >> 6;

    // ---- click NN over 4096 points, 16 pts/thread ----
    float cx = cq[row*3+0];
    float cy = cq[row*3+1];
    float cz = cq[row*3+2];
    const float* ex = enc_xyz + (size_t)b * 4096 * 3;
    float nbest = 3.4e38f; int nbidx = 0;
#pragma unroll
    for (int i = 0; i < 16; i++) {
        int p = t + i*256;
        float dx = cx - ex[p*3+0];
        float dy = cy - ex[p*3+1];
        float dz = cz - ex[p*3+2];
        float d = dx*dx + dy*dy;
        d = d + dz*dz;
        if (d < nbest) { nbest = d; nbidx = p; }   // strict <, p ascending -> first min
    }
#pragma unroll
    for (int off = 32; off; off >>= 1) {
        float ov = __shfl_down(nbest, off);
        int   oi = __shfl_down(nbidx, off);
        if (ov < nbest || (ov == nbest && oi < nbidx)) { nbest = ov; nbidx = oi; }
    }
    if (lane == 0) { nnd[wave] = nbest; nni[wave] = nbidx; }

    // ---- box match: this thread owns proposal p = t ----
    float iou; int pidx = t;
    {
        const float* c = corners + ((size_t)b*256 + t) * 24;
        float mn0 = c[0], mn1 = c[1], mn2 = c[2];
        float mx0 = mn0, mx1 = mn1, mx2 = mn2;
#pragma unroll
        for (int k = 1; k < 8; k++) {
            float v0 = c[k*3+0], v1 = c[k*3+1], v2 = c[k*3+2];
            mn0 = fminf(mn0, v0); mx0 = fmaxf(mx0, v0);
            mn1 = fminf(mn1, v1); mx1 = fmaxf(mx1, v1);
            mn2 = fminf(mn2, v2); mx2 = fmaxf(mx2, v2);
        }
        float pvol = (mx0-mn0)*(mx1-mn1)*(mx2-mn2);
        const float* lg = logits + ((size_t)b*256 + t) * 19;
        float bv = lg[0]; int bi = 0;
#pragma unroll
        for (int k = 1; k < 19; k++) { float v = lg[k]; if (v > bv) { bv = v; bi = k; } }
        float pmsk = (bi != 18) ? 1.0f : 0.0f;

        // query AABB (same for all threads in block)
        const float* qc = box_query + (size_t)row * 24;
        float qn0 = qc[0], qn1 = qc[1], qn2 = qc[2];
        float qx0 = qn0, qx1 = qn1, qx2 = qn2;
#pragma unroll
        for (int k = 1; k < 8; k++) {
            float v0 = qc[k*3+0], v1 = qc[k*3+1], v2 = qc[k*3+2];
            qn0 = fminf(qn0, v0); qx0 = fmaxf(qx0, v0);
            qn1 = fminf(qn1, v1); qx1 = fmaxf(qx1, v1);
            qn2 = fminf(qn2, v2); qx2 = fmaxf(qx2, v2);
        }
        float qvol = (qx0-qn0)*(qx1-qn1)*(qx2-qn2);
        float e0 = fminf(qx0, mx0) - fmaxf(qn0, mn0); e0 = fmaxf(e0, 0.0f);
        float e1 = fminf(qx1, mx1) - fmaxf(qn1, mn1); e1 = fmaxf(e1, 0.0f);
        float e2 = fminf(qx2, mx2) - fmaxf(qn2, mn2); e2 = fmaxf(e2, 0.0f);
        float inter = (e0*e1)*e2;
        iou = inter / (qvol + pvol - inter + 1e-8f) * pmsk;
    }
#pragma unroll
    for (int off = 32; off; off >>= 1) {
        float ov = __shfl_down(iou, off);
        int   oi = __shfl_down(pidx, off);
        if (ov > iou || (ov == iou && oi < pidx)) { iou = ov; pidx = oi; }
    }
    if (lane == 0) { bxd[wave] = iou; bxi[wave] = pidx; }
    __syncthreads();
    if (t == 0) {
        float nv = nnd[0]; int ni = nni[0];
        float bv = bxd[0]; int bi = bxi[0];
#pragma unroll
        for (int w = 1; w < 4; w++) {
            if (nnd[w] < nv || (nnd[w] == nv && nni[w] < ni)) { nv = nnd[w]; ni = nni[w]; }
            if (bxd[w] > bv || (bxd[w] == bv && bxi[w] < bi)) { bv = bxd[w]; bi = bxi[w]; }
        }
        s_nn = ni; s_match = bi;
    }
    __syncthreads();
    int nnid = s_nn, match = s_match;

    // ---- gathers + fourier pos embed ----
    box_in[(size_t)row*256 + t] =
        (_Float16)prop_features[((size_t)b*256 + match)*256 + t];
    click_in[(size_t)row*512 + t] =
        (_Float16)enc_features[((size_t)b*4096 + nnid)*256 + t];
    int j = t & 127;
    float m0 = pc_min[b*3+0], m1 = pc_min[b*3+1], m2 = pc_min[b*3+2];
    float tx = (cx - m0) / (pc_max[b*3+0] - m0) * TWO_PI;
    float ty = (cy - m1) / (pc_max[b*3+1] - m1) * TWO_PI;
    float tz = (cz - m2) / (pc_max[b*3+2] - m2) * TWO_PI;
    float p = tx * gB[j] + ty * gB[128+j] + tz * gB[256+j];
    float v = (t < 128) ? sinf(p) : cosf(p);
    click_in[(size_t)row*512 + 256 + t] = (_Float16)v;
    // prompt mask: 16 elements per row-block
    if (t < 16) {
        int idx = row*16 + t;            // 0..32767
        int mb = idx >> 10, i = idx & 1023;
        float mv = (i < 512) ? box_qmask[mb*64 + (i >> 3)]
                             : click_qmask[mb*64 + ((i - 512) >> 3)];
        out[25165824 + idx] = mv;
    }
}

// ------------------------------------------------------------------
// f16 MFMA GEMM core: C[M,N] = A[M,K] @ Bt[N,K]^T + bias
// 128x128 tile, BK=64, XOR-swizzled LDS (conflict-free ds_read_b128),
// global_load_lds width-16 staging. K % 64 == 0.
// MODE 0: relu -> f16 Hout (row-major, stride N)
// MODE 1: fp32 -> Fout, prompt reshape: off=(m>>6)*786432+brOff+(m&63)*6144+n
// ------------------------------------------------------------------
template<int MODE>
__device__ __forceinline__ void gemm_core(
    const _Float16* __restrict__ A, const _Float16* __restrict__ Bt,
    const float* __restrict__ bias, int N, int K,
    _Float16* __restrict__ Hout, float* __restrict__ Fout, long brOff,
    int bm, int bn, _Float16* As, _Float16* Bs)
{
    const int tid = threadIdx.x;
    const int wave = tid >> 6, lane = tid & 63;
    const int waveM = (wave & 1) * 64, waveN = (wave >> 1) * 64;
    const int nrow = lane & 15;         // fragment row within 16
    const int kq   = lane >> 4;         // fragment k quarter (0..3)

    const int srow = tid >> 3;                                  // 0..31
    const int jdat = ((tid & 7) ^ (srow & 7)) * 8;              // half offset

    floatx4 acc[4][4];
#pragma unroll
    for (int i = 0; i < 4; i++)
#pragma unroll
        for (int j = 0; j < 4; j++) { floatx4 z = {0.f,0.f,0.f,0.f}; acc[i][j] = z; }

    const _Float16* Ab[4]; const _Float16* Bb[4];
    _Float16 *lA[4], *lB[4];
#pragma unroll
    for (int q = 0; q < 4; q++) {
        Ab[q] = A  + (size_t)(bm*128 + q*32 + srow) * K + jdat;
        Bb[q] = Bt + (size_t)(bn*128 + q*32 + srow) * K + jdat;
        lA[q] = As + q*2048 + wave*512;
        lB[q] = Bs + q*2048 + wave*512;
    }

    for (int kk = 0; kk < K; kk += 64) {
        __syncthreads();                 // prior-tile LDS reads done
#pragma unroll
        for (int q = 0; q < 4; q++) async16(Ab[q] + kk, lA[q]);
#pragma unroll
        for (int q = 0; q < 4; q++) async16(Bb[q] + kk, lB[q]);
        __syncthreads();                 // staging complete
#pragma unroll
        for (int h = 0; h < 2; h++) {
            const int sw = (((kq + h*4) ^ (nrow & 7)) * 8);
            half8 af[4], bf[4];
#pragma unroll
            for (int i = 0; i < 4; i++)
                af[i] = *(const half8*)(As + (waveM + i*16 + nrow)*64 + sw);
#pragma unroll
            for (int j = 0; j < 4; j++)
                bf[j] = *(const half8*)(Bs + (waveN + j*16 + nrow)*64 + sw);
#pragma unroll
            for (int i = 0; i < 4; i++)
#pragma unroll
                for (int j = 0; j < 4; j++)
                    acc[i][j] = __builtin_amdgcn_mfma_f32_16x16x32_f16(af[i], bf[j], acc[i][j], 0, 0, 0);
        }
    }

    // epilogue: C/D layout col = lane&15, row = (lane>>4)*4 + reg
#pragma unroll
    for (int i = 0; i < 4; i++) {
#pragma unroll
        for (int j = 0; j < 4; j++) {
            int col = bn*128 + waveN + j*16 + nrow;
            float bv = bias[col];
#pragma unroll
            for (int r = 0; r < 4; r++) {
                int row = bm*128 + waveM + i*16 + kq*4 + r;
                float v = acc[i][j][r] + bv;
                if (MODE == 0) {
                    v = v > 0.f ? v : 0.f;
                    Hout[(size_t)row * N + col] = (_Float16)v;
                } else {
                    size_t off = (size_t)(row >> 6) * 786432 + (size_t)brOff
                               + (size_t)(row & 63) * 6144 + col;
                    Fout[off] = v;
                }
            }
        }
    }
}

// ------------------------------------------------------------------
// Launch 2: layer-1 GEMM blocks [0,192) + w2 transposes [192,2496).
// No dependency between the two halves; the 2304 transpose blocks
// fill the machine while the 192 GEMM blocks run.
// ------------------------------------------------------------------
__global__ __launch_bounds__(256) void gemm_l1_t2(
    const _Float16* __restrict__ A0, const _Float16* __restrict__ A1,
    const _Float16* __restrict__ B0, const _Float16* __restrict__ B1,
    const float* __restrict__ b0, const float* __restrict__ b1,
    _Float16* __restrict__ H0, _Float16* __restrict__ H1,
    const float* __restrict__ bw2, const float* __restrict__ cw2,
    _Float16* __restrict__ w2t_box, _Float16* __restrict__ w2t_clk)
{
    __shared__ _Float16 As[8192];
    __shared__ _Float16 Bs[8192];
    int bid = blockIdx.x;
    if (bid < 192) {
        int z = bid / 96, r = bid % 96;
        int bm = r % 16, bn = r / 16;     // (16,6)
        if (z == 0)
            gemm_core<0>(A0, B0, b0, 768, 256, H0, nullptr, 0, bm, bn, As, Bs);
        else
            gemm_core<0>(A1, B1, b1, 768, 512, H1, nullptr, 0, bm, bn, As, Bs);
    } else {
        int r = bid - 192;                // 0..2303 = (96,12,2)
        int x = r % 96, y = (r / 96) % 12, z = r / 1152;
        if (z == 0) transpose_core(bw2, w2t_box, 768, 6144, As, x, y);
        else        transpose_core(cw2, w2t_clk, 768, 6144, As, x, y);
    }
}

// ------------------------------------------------------------------
// Layer-2 GEMM (verified 128^2 core): both branches (z: 0=box, 1=click),
// N=6144, K=768. XCD-aware bijective remap: 768 blocks/branch; each XCD
// (lin%8) gets a contiguous bn range of 6 tiles -> per-XCD L2 holds the
// full A panel (3MB) + its B slice (1.2MB).
// ------------------------------------------------------------------
__global__ __launch_bounds__(256) void gemm_l2(
    const _Float16* __restrict__ A0, const _Float16* __restrict__ A1,
    const _Float16* __restrict__ B0, const _Float16* __restrict__ B1,
    const float* __restrict__ b0, const float* __restrict__ b1,
    float* __restrict__ out)
{
    __shared__ _Float16 As[8192];
    __shared__ _Float16 Bs[8192];
    int lin = blockIdx.x + 16 * blockIdx.y;   // 0..767
    int xcd = lin & 7;
    int per = lin >> 3;                        // 0..95
    int bm  = per & 15;                        // 0..15  (per%16)
    int bn  = xcd * 6 + (per >> 4);            // 0..47  (bijective: 48%8==0)
    if (blockIdx.z == 0)
        gemm_core<1>(A0, B0, b0, 6144, 768, nullptr, out, 0,      bm, bn, As, Bs);
    else
        gemm_core<1>(A1, B1, b1, 6144, 768, nullptr, out, 393216, bm, bn, As, Bs);
}

// ------------------------------------------------------------------
extern "C" void kernel_launch(void* const* d_in, const int* in_sizes, int n_in,
                              void* d_out, int out_size, void* d_ws, size_t ws_size,
                              hipStream_t stream)
{
    const float* sem   = (const float*)d_in[0];
    const float* propf = (const float*)d_in[1];
    const float* boxc  = (const float*)d_in[2];
    const float* encx  = (const float*)d_in[3];
    const float* encf  = (const float*)d_in[4];
    const float* pcmin = (const float*)d_in[5];
    const float* pcmax = (const float*)d_in[6];
    const float* boxq  = (const float*)d_in[7];
    const float* boxm  = (const float*)d_in[8];
    const float* clkq  = (const float*)d_in[9];
    const float* clkm  = (const float*)d_in[10];
    const float* gB    = (const float*)d_in[11];
    const float* bw1   = (const float*)d_in[12];
    const float* bb1   = (const float*)d_in[13];
    const float* bw2   = (const float*)d_in[14];
    const float* bb2   = (const float*)d_in[15];
    const float* cw1   = (const float*)d_in[16];
    const float* cb1   = (const float*)d_in[17];
    const float* cw2   = (const float*)d_in[18];
    const float* cb2   = (const float*)d_in[19];
    float* out = (float*)d_out;
    char* ws = (char*)d_ws;

    _Float16* box_in   = (_Float16*)(ws + 278528);    // 2048x256
    _Float16* click_in = (_Float16*)(ws + 1327104);   // 2048x512
    _Float16* h_box    = (_Float16*)(ws + 3424256);   // 2048x768
    _Float16* h_click  = (_Float16*)(ws + 6569984);   // 2048x768
    _Float16* w1t_box  = (_Float16*)(ws + 9715712);   // 768x256
    _Float16* w2t_box  = (_Float16*)(ws + 10108928);  // 6144x768
    _Float16* w1t_clk  = (_Float16*)(ws + 19546112);  // 768x512
    _Float16* w2t_clk  = (_Float16*)(ws + 20332544);  // 6144x768

    // K1: w1 transposes + per-row front-end
    mega_prep<<<2240, 256, 0, stream>>>(sem, boxc, boxq,
                                        bw1, cw1, w1t_box, w1t_clk,
                                        propf, encf, encx, clkq,
                                        pcmin, pcmax, gB, boxm, clkm,
                                        box_in, click_in, out);
    // K2: layer-1 GEMM + w2 transposes (independent, one launch)
    gemm_l1_t2<<<2496, 256, 0, stream>>>(box_in, click_in, w1t_box, w1t_clk,
                                         bb1, cb1, h_box, h_click,
                                         bw2, cw2, w2t_box, w2t_clk);
    // K3: layer-2 GEMM, verified 128^2 core + XCD remap
    gemm_l2<<<dim3(16, 48, 2), 256, 0, stream>>>(h_box, h_click, w2t_box, w2t_clk,
                                                 bb2, cb2, out);
}